// Round 5
// baseline (123.542 us; speedup 1.0000x reference)
//
#include <hip/hip_runtime.h>

// KANConv2d, round 5: feature-precompute split.
//   kan_wprep : combined bf16 weights Wb[cb][tap][c_l][o][j]           (1.2 MB ws)
//   kan_feat  : feature granules (8 bf16: silu, B_0..B_6) per PADDED pixel,
//               layout feat[(b*C+c)*66 + hp][wp], halo = f(0) automatically (71 MB ws)
//   kan_mfma2 : implicit GEMM; B staged by global_load_lds (zero-VALU DMA),
//               wave = 128o x 32w x 1h (4x oi reuse), setprio around MFMA cluster.
// Fallback to the fused R4 kernel if ws_size can't hold the feature tensor.

#define BB 16
#define CC 64
#define HH 64
#define WW 64
#define OO 128
#define FH 66
#define FW 66

typedef __bf16 bf16x8 __attribute__((ext_vector_type(8)));
typedef float f32x16 __attribute__((ext_vector_type(16)));

__device__ __forceinline__ bf16x8 as_bf16x8(uint4 v) { return __builtin_bit_cast(bf16x8, v); }
__device__ __forceinline__ unsigned bfb(float f) {
    return (unsigned)__builtin_bit_cast(unsigned short, (__bf16)f);
}

// 8-feature granule {silu(v), B_0(v)..B_6(v)} packed as 8 bf16.
// Cardinal cubic B-spline: t = 2v+5, nonzero slots s0..s0+3 (s0 = floor(t)-3),
// placed via 128-bit funnel shift; slot 0 then overwritten with silu.
__device__ __forceinline__ uint4 feat_granule(float v) {
    const float silu = __fdividef(v, 1.f + __expf(-v));
    const float t  = fmaf(2.f, v, 5.f);
    const float fi = floorf(t);
    const float u  = t - fi;
    const float um = 1.f - u;
    const float u2 = u * u, u3 = u2 * u;
    const float k0 = um * um * um * (1.f / 6.f);
    const float k1 = fmaf(0.5f, u3, (2.f / 3.f) - u2);
    const float k2 = fmaf(-0.5f, u3, fmaf(0.5f, u2, fmaf(0.5f, u, 1.f / 6.f)));
    const float k3 = u3 * (1.f / 6.f);
    const bool valid = (t >= 0.f) && (t < 10.f);
    unsigned long long K =
        (unsigned long long)bfb(k0)         |
        ((unsigned long long)bfb(k1) << 16) |
        ((unsigned long long)bfb(k2) << 32) |
        ((unsigned long long)bfb(k3) << 48);
    if (!valid) K = 0ull;
    const int ic = min(max((int)fi, -2), 9);
    const int sh = 16 * ic - 32;            // [-64, 112]
    unsigned __int128 P = (sh >= 0) ? ((unsigned __int128)K << sh)
                                    : ((unsigned __int128)K >> (-sh));
    uint4 pk = __builtin_bit_cast(uint4, P);
    pk.x = (pk.x & 0xFFFF0000u) | bfb(silu);
    return pk;
}

// ---------------- weight prep: Wb[cb][tap][c_l][o][j] bf16, j contiguous ----------------
__global__ __launch_bounds__(256) void kan_wprep(
    const float* __restrict__ beta, const float* __restrict__ spl,
    const float* __restrict__ cf, uint4* __restrict__ wb)
{
    int t = blockIdx.x * 256 + threadIdx.x;      // 73728 = (o, c, tap)
    int tap = t % 9;
    int c   = (t / 9) & 63;
    int o   = t / 576;
    int base = (o * CC + c) * 9 + tap;
    float bv = beta[base];
    float sv = spl[base];
    float f[8];
    f[0] = bv;
    #pragma unroll
    for (int s = 0; s < 7; ++s)
        f[1 + s] = sv * cf[((s * OO + o) * CC + c) * 9 + tap];
    uint4 pk;
    pk.x = bfb(f[0]) | (bfb(f[1]) << 16);
    pk.y = bfb(f[2]) | (bfb(f[3]) << 16);
    pk.z = bfb(f[4]) | (bfb(f[5]) << 16);
    pk.w = bfb(f[6]) | (bfb(f[7]) << 16);
    int cb = c >> 2, cl = c & 3;
    wb[((cb * 9 + tap) * 4 + cl) * OO + o] = pk;
}

// ---------------- feature tensor over the PADDED domain ----------------
__global__ __launch_bounds__(256) void kan_feat(
    const float* __restrict__ x, uint4* __restrict__ feat)
{
    const int t  = blockIdx.x * 256 + threadIdx.x;   // 16*64*66*66 = 4460544 exactly
    const int w  = t % FW;
    const int h  = (t / FW) % FH;
    const int bc = t / (FH * FW);
    float v = 0.f;
    if (h >= 1 && h <= HH && w >= 1 && w <= WW)
        v = x[(bc * HH + (h - 1)) * WW + (w - 1)];
    feat[t] = feat_granule(v);
}

// ---------------- main implicit GEMM ----------------
__global__ __launch_bounds__(256, 2) void kan_mfma2(
    const uint4* __restrict__ wb, const uint4* __restrict__ feat,
    float* __restrict__ out)
{
    // [buf][c_l][padded row r 0..5][granule col 0..63]
    __shared__ uint4 ft[2][4][6][64];

    const int tid  = threadIdx.x;
    const int blk  = blockIdx.x;
    const int wh   = blk & 1;          // w half (32 cols)
    const int hq   = (blk >> 1) & 15;  // h quad (4 rows)
    const int b    = blk >> 5;

    const int ww   = tid >> 6;         // wave 0..3 = output row within quad
    const int lane = tid & 63;
    const int lo   = lane & 31;
    const int hi   = lane >> 5;

    const int h0  = hq << 2;           // padded-row base; rows h0..h0+5 staged
    const int wg0 = wh << 5;           // padded-col granule base

    f32x16 acc[4] = {};

    // stage channel-block cbi into ft[bufi]: wave ww DMAs cl=ww, 6 rows x 64 granules
    #define STAGE2(bufi, cbi) do {                                            \
        const uint4* src = feat +                                             \
            (size_t)((b * CC + (cbi) * 4 + ww) * FH + h0) * FW + wg0 + lane;  \
        _Pragma("unroll")                                                     \
        for (int r = 0; r < 6; ++r)                                           \
            __builtin_amdgcn_global_load_lds(                                 \
                (const __attribute__((address_space(1))) void*)(src + r * FW),\
                (__attribute__((address_space(3))) void*)&ft[bufi][ww][r][0], \
                16, 0, 0);                                                    \
    } while (0)

    uint4 A0[2][4], A1[2][4];
    #define LOADA2(dst, cbi, tapi) do {                                       \
        _Pragma("unroll")                                                     \
        for (int kh = 0; kh < 2; ++kh) {                                      \
            const uint4* wr = wb +                                            \
                ((((cbi) * 9 + (tapi)) * 4 + kh * 2 + hi) * OO) + lo;         \
            _Pragma("unroll")                                                 \
            for (int oi = 0; oi < 4; ++oi) dst[kh][oi] = wr[oi * 32];         \
        }                                                                     \
    } while (0)

    STAGE2(0, 0);
    __syncthreads();

    #pragma unroll 1
    for (int cb = 0; cb < 16; ++cb) {
        const int buf = cb & 1;
        if (cb < 15) STAGE2(buf ^ 1, cb + 1);   // DMA next channel-block early
        LOADA2(A0, cb, 0);

        #pragma unroll
        for (int tap = 0; tap < 9; ++tap) {
            const int dh = tap / 3;
            const int dw = tap % 3;
            if (tap < 8) {                       // A depth-1 prefetch
                if (tap & 1) LOADA2(A0, cb, tap + 1);
                else         LOADA2(A1, cb, tap + 1);
            }
            bf16x8 Bf[2];
            #pragma unroll
            for (int kh = 0; kh < 2; ++kh)
                Bf[kh] = as_bf16x8(ft[buf][kh * 2 + hi][ww + dh][dw + lo]);
            uint4 (&A)[2][4] = (tap & 1) ? A1 : A0;
            __builtin_amdgcn_s_setprio(1);
            #pragma unroll
            for (int oi = 0; oi < 4; ++oi)
                #pragma unroll
                for (int kh = 0; kh < 2; ++kh)
                    acc[oi] = __builtin_amdgcn_mfma_f32_32x32x16_bf16(
                        as_bf16x8(A[kh][oi]), Bf[kh], acc[oi], 0, 0, 0);
            __builtin_amdgcn_s_setprio(0);
        }
        __syncthreads();    // drains vmcnt(0): stage for cb+1 landed; LDS safe to swap
    }

    // D row = o (A row), col = pixel w -> w-coalesced dword stores
    const int h  = h0 + ww;
    const int wc = wg0 + lo;
    #pragma unroll
    for (int oi = 0; oi < 4; ++oi)
        #pragma unroll
        for (int r = 0; r < 16; ++r) {
            const int o = oi * 32 + (r & 3) + ((r >> 2) << 3) + (hi << 2);
            out[((b * OO + o) * HH + h) * WW + wc] = acc[oi][r];
        }
}

// ---------------- fallback: R4 fused kernel (verified at 103 us) ----------------
__global__ __launch_bounds__(512, 4) void kan_mfma_fused(
    const float* __restrict__ x, const uint4* __restrict__ wb,
    float* __restrict__ out)
{
    __shared__ uint4 ft[2][4 * 4 * 66];

    const int tid  = threadIdx.x;
    const int blk  = blockIdx.x;
    const int h0   = (blk & 31) << 1;
    const int b    = blk >> 5;

    const int ww    = tid >> 6;
    const int lane  = tid & 63;
    const int lo    = lane & 31;
    const int hi    = lane >> 5;
    const int ohalf = ww & 1;
    const int hrow  = (ww >> 1) & 1;
    const int wtile = ww >> 2;

    const int scl  = (tid >> 5) & 3;
    const int srow = tid >> 7;
    const int swp0 = tid & 31;
    const int hp   = h0 - 1 + srow;
    const bool hok = (unsigned)hp < 64u;

    f32x16 acc[2] = {};
    float xn[3];

    #define LOADX(cbi) do {                                                   \
        const int c_ = (cbi) * 4 + scl;                                       \
        const float* xr = x + ((b * CC + c_) * HH + hp) * WW;                 \
        _Pragma("unroll")                                                     \
        for (int it = 0; it < 3; ++it) {                                      \
            const int wx = swp0 + it * 32 - 1;                                \
            const bool act = (it < 2 || swp0 < 2) && hok &&                   \
                             ((unsigned)wx < 64u);                            \
            xn[it] = act ? xr[wx] : 0.f;                                      \
        }                                                                     \
    } while (0)

    #define STAGEF(bufi) do {                                                 \
        _Pragma("unroll")                                                     \
        for (int it = 0; it < 3; ++it) {                                      \
            if (it < 2 || swp0 < 2) {                                         \
                const int wp = swp0 + it * 32;                                \
                ft[bufi][(scl * 4 + srow) * 66 + wp] = feat_granule(xn[it]);  \
            }                                                                 \
        }                                                                     \
    } while (0)

    uint4 A0[2][2], A1[2][2];
    #define LOADAF(dst, cbi, tapi) do {                                       \
        _Pragma("unroll")                                                     \
        for (int kh = 0; kh < 2; ++kh) {                                      \
            const int cl = kh * 2 + hi;                                       \
            const uint4* wr = wb + (((cbi) * 9 + (tapi)) * 4 + cl) * OO       \
                              + ohalf * 64 + lo;                              \
            dst[kh][0] = wr[0];                                               \
            dst[kh][1] = wr[32];                                              \
        }                                                                     \
    } while (0)

    LOADX(0);
    STAGEF(0);
    __syncthreads();

    #pragma unroll 1
    for (int cb = 0; cb < 16; ++cb) {
        const int buf = cb & 1;
        if (cb < 15) LOADX(cb + 1);
        LOADAF(A0, cb, 0);
        const uint4* ftb = ft[buf];

        #pragma unroll
        for (int tap = 0; tap < 9; ++tap) {
            const int dh = tap / 3;
            const int dw = tap % 3;
            if (tap < 8) {
                if (tap & 1) LOADAF(A0, cb, tap + 1);
                else         LOADAF(A1, cb, tap + 1);
            }
            bf16x8 Bf[2];
            #pragma unroll
            for (int kh = 0; kh < 2; ++kh) {
                const int cl = kh * 2 + hi;
                const uint4* fr = ftb + (cl * 4 + hrow + dh) * 66
                                  + wtile * 32 + dw + lo;
                Bf[kh] = as_bf16x8(fr[0]);
            }
            uint4 (&A)[2][2] = (tap & 1) ? A1 : A0;
            #pragma unroll
            for (int oi = 0; oi < 2; ++oi)
                #pragma unroll
                for (int kh = 0; kh < 2; ++kh)
                    acc[oi] = __builtin_amdgcn_mfma_f32_32x32x16_bf16(
                        as_bf16x8(A[kh][oi]), Bf[kh], acc[oi], 0, 0, 0);
        }

        if (cb < 15) STAGEF(buf ^ 1);
        __syncthreads();
    }

    const int h  = h0 + hrow;
    const int wc = wtile * 32 + lo;
    #pragma unroll
    for (int oi = 0; oi < 2; ++oi)
        #pragma unroll
        for (int r = 0; r < 16; ++r) {
            const int o = ohalf * 64 + oi * 32 + (r & 3) + ((r >> 2) << 3) + (hi << 2);
            out[((b * OO + o) * HH + h) * WW + wc] = acc[oi][r];
        }
}

extern "C" void kernel_launch(void* const* d_in, const int* in_sizes, int n_in,
                              void* d_out, int out_size, void* d_ws, size_t ws_size,
                              hipStream_t stream) {
    const float* x    = (const float*)d_in[0];
    const float* beta = (const float*)d_in[1];
    const float* spl  = (const float*)d_in[2];
    const float* cf   = (const float*)d_in[3];
    float* out = (float*)d_out;

    uint4* wb = (uint4*)d_ws;                           // 73728 granules = 1.18 MB
    const size_t WB_G   = 73728;
    const size_t FEAT_G = (size_t)BB * CC * FH * FW;    // 4460544 granules = 71.4 MB
    const size_t NEED   = (WB_G + FEAT_G) * 16 + 1024;  // +1KB tail pad for 64-lane DMA

    kan_wprep<<<288, 256, 0, stream>>>(beta, spl, cf, wb);

    if (ws_size >= NEED) {
        uint4* feat = wb + WB_G;
        kan_feat<<<(int)(FEAT_G / 256), 256, 0, stream>>>(x, feat);
        kan_mfma2<<<BB * 16 * 2, 256, 0, stream>>>(wb, feat, out);
    } else {
        kan_mfma_fused<<<BB * (HH / 2), 512, 0, stream>>>(x, wb, out);
    }
}

// Round 6
// 90.218 us; speedup vs baseline: 1.3694x; 1.3694x over previous
//
#include <hip/hip_runtime.h>

// KANConv2d, round 6: weights-in-LDS implicit GEMM.
// out[b,o,h,w] = sum_{c,tap,j} Wc[o,c,tap,j] * f_j(xp[b,c,h+dh,w+dw])
// f = {silu(v), B_0..B_6(v)} cardinal cubic B-splines (t = 2v+5), 8 bf16/granule.
// Structure: grid 256 (b x hquad), 1 block/CU, 8 waves (wave = 64o x 64w x 1h).
//   A (combined weights) DMA'd to LDS, double-buffered per 3-tap substep (48 substeps).
//   B (features) computed in-kernel from x, double-buffered per channel-block (cb).
//   All LDS reads lane-consecutive 16B granules (conflict-free).

#define BB 16
#define CC 64
#define HH 64
#define WW 64
#define OO 128

typedef __bf16 bf16x8 __attribute__((ext_vector_type(8)));
typedef float f32x16 __attribute__((ext_vector_type(16)));

__device__ __forceinline__ bf16x8 as_bf16x8(uint4 v) { return __builtin_bit_cast(bf16x8, v); }
__device__ __forceinline__ unsigned bfb(float f) {
    return (unsigned)__builtin_bit_cast(unsigned short, (__bf16)f);
}

// 8-feature granule {silu(v), B_0(v)..B_6(v)} packed as 8 bf16 via 128-bit shift scatter.
__device__ __forceinline__ uint4 feat_granule(float v) {
    const float silu = __fdividef(v, 1.f + __expf(-v));
    const float t  = fmaf(2.f, v, 5.f);
    const float fi = floorf(t);
    const float u  = t - fi;
    const float um = 1.f - u;
    const float u2 = u * u, u3 = u2 * u;
    const float k0 = um * um * um * (1.f / 6.f);
    const float k1 = fmaf(0.5f, u3, (2.f / 3.f) - u2);
    const float k2 = fmaf(-0.5f, u3, fmaf(0.5f, u2, fmaf(0.5f, u, 1.f / 6.f)));
    const float k3 = u3 * (1.f / 6.f);
    const bool valid = (t >= 0.f) && (t < 10.f);
    unsigned long long K =
        (unsigned long long)bfb(k0)         |
        ((unsigned long long)bfb(k1) << 16) |
        ((unsigned long long)bfb(k2) << 32) |
        ((unsigned long long)bfb(k3) << 48);
    if (!valid) K = 0ull;
    const int ic = min(max((int)fi, -2), 9);
    const int sh = 16 * ic - 32;            // [-64, 112]
    unsigned __int128 P = (sh >= 0) ? ((unsigned __int128)K << sh)
                                    : ((unsigned __int128)K >> (-sh));
    uint4 pk = __builtin_bit_cast(uint4, P);
    pk.x = (pk.x & 0xFFFF0000u) | bfb(silu);
    return pk;
}

// ---------------- weight prep: Wb[cb][tap][c_l][o][j] bf16, j contiguous ----------------
__global__ __launch_bounds__(256) void kan_wprep(
    const float* __restrict__ beta, const float* __restrict__ spl,
    const float* __restrict__ cf, uint4* __restrict__ wb)
{
    int t = blockIdx.x * 256 + threadIdx.x;      // 73728 = (o, c, tap)
    int tap = t % 9;
    int c   = (t / 9) & 63;
    int o   = t / 576;
    int base = (o * CC + c) * 9 + tap;
    float bv = beta[base];
    float sv = spl[base];
    float f[8];
    f[0] = bv;
    #pragma unroll
    for (int s = 0; s < 7; ++s)
        f[1 + s] = sv * cf[((s * OO + o) * CC + c) * 9 + tap];
    uint4 pk;
    pk.x = bfb(f[0]) | (bfb(f[1]) << 16);
    pk.y = bfb(f[2]) | (bfb(f[3]) << 16);
    pk.z = bfb(f[4]) | (bfb(f[5]) << 16);
    pk.w = bfb(f[6]) | (bfb(f[7]) << 16);
    int cb = c >> 2, cl = c & 3;
    wb[((cb * 9 + tap) * 4 + cl) * OO + o] = pk;
}

// ---------------- main implicit GEMM, weights + features both in LDS ----------------
__global__ __launch_bounds__(512, 2) void kan_mfma3(
    const float* __restrict__ x, const uint4* __restrict__ wb,
    float* __restrict__ out)
{
    // B/features: [buf][(cl*6 + row)*66 + col], 1584 granules/buf
    __shared__ uint4 Bt[2][1584];
    // A/weights substep tile: [buf][(tl*4 + cl)*128 + o], 1536 granules/buf
    __shared__ uint4 At[2][1536];

    const int tid  = threadIdx.x;
    const int blk  = blockIdx.x;
    const int hq   = blk & 15;
    const int b    = blk >> 4;
    const int h0   = hq << 2;          // output rows h0..h0+3; input rows h0-1..h0+4

    const int ww    = tid >> 6;        // wave 0..7
    const int lane  = tid & 63;
    const int lo    = lane & 31;
    const int hi    = lane >> 5;
    const int ohalf = ww & 1;
    const int hrow  = ww >> 1;         // 0..3

    f32x16 acc[2][2] = {};             // [oi][wi]
    float xv[4];

    // ---- x loads for channel-block cbi: 1584 granule-pixels, ~3.1/thread ----
    #define XLOAD(cbi) do {                                                   \
        _Pragma("unroll")                                                     \
        for (int k = 0; k < 4; ++k) {                                         \
            const int g = tid + k * 512;                                      \
            float v = 0.f;                                                    \
            if (g < 1584) {                                                   \
                const int cl_ = g / 396;                                      \
                const int r_  = (g % 396) / 66;                               \
                const int co_ = g % 66;                                       \
                const int hp  = h0 - 1 + r_;                                  \
                const int wx  = co_ - 1;                                      \
                if ((unsigned)hp < 64u && (unsigned)wx < 64u)                 \
                    v = x[((b * CC + (cbi) * 4 + cl_) * HH + hp) * WW + wx];  \
            }                                                                 \
            xv[k] = v;                                                        \
        }                                                                     \
    } while (0)

    // ---- feature compute + LDS write into Bt[bufi] ----
    #define FEATW(bufi) do {                                                  \
        _Pragma("unroll")                                                     \
        for (int k = 0; k < 4; ++k) {                                         \
            const int g = tid + k * 512;                                      \
            if (g < 1584) Bt[bufi][g] = feat_granule(xv[k]);                  \
        }                                                                     \
    } while (0)

    // ---- DMA one A substep slice (cb1, dh1) into At[bufi]: 24 x 1KB, 3/wave ----
    #define ADMA(bufi, cb1, dh1) do {                                         \
        const uint4* asrc = wb + ((cb1) * 4608 + (dh1) * 1536)                \
                            + ww * 192 + lane;                                \
        _Pragma("unroll")                                                     \
        for (int i = 0; i < 3; ++i)                                           \
            __builtin_amdgcn_global_load_lds(                                 \
                (const __attribute__((address_space(1))) void*)(asrc + i*64), \
                (__attribute__((address_space(3))) void*)                     \
                    &At[bufi][ww * 192 + i * 64],                             \
                16, 0, 0);                                                    \
    } while (0)

    // prologue: x + features for cb=0, A substep 0
    XLOAD(0);
    ADMA(0, 0, 0);
    FEATW(0);
    __syncthreads();

    #pragma unroll 1
    for (int cb = 0; cb < 16; ++cb) {
        const uint4* Bb = Bt[cb & 1];

        #pragma unroll
        for (int dh = 0; dh < 3; ++dh) {
            const int buf = (cb + dh) & 1;       // s = cb*3+dh; s&1 == (cb+dh)&1

            // stage next A substep (lands during this substep's MFMAs)
            if (cb < 15 || dh < 2) {
                const int cb1 = (dh == 2) ? cb + 1 : cb;
                const int dh1 = (dh == 2) ? 0 : dh + 1;
                ADMA(buf ^ 1, cb1, dh1);
            }
            if (dh == 0 && cb < 15) XLOAD(cb + 1);   // issue-early (T14)

            const uint4* Ab = At[buf];
            #pragma unroll
            for (int tl = 0; tl < 3; ++tl) {         // tap = dh*3+tl, dw = tl
                bf16x8 Af[2][2], Bf[2][2];           // [kh][oi] / [kh][wi]
                #pragma unroll
                for (int kh = 0; kh < 2; ++kh) {
                    const int arow = (tl * 4 + kh * 2 + hi) * 128 + ohalf * 64 + lo;
                    Af[kh][0] = as_bf16x8(Ab[arow]);
                    Af[kh][1] = as_bf16x8(Ab[arow + 32]);
                    const int brow = ((kh * 2 + hi) * 6 + hrow + dh) * 66 + tl + lo;
                    Bf[kh][0] = as_bf16x8(Bb[brow]);
                    Bf[kh][1] = as_bf16x8(Bb[brow + 32]);
                }
                __builtin_amdgcn_s_setprio(1);
                #pragma unroll
                for (int oi = 0; oi < 2; ++oi)
                    #pragma unroll
                    for (int wi = 0; wi < 2; ++wi)
                        #pragma unroll
                        for (int kh = 0; kh < 2; ++kh)
                            acc[oi][wi] = __builtin_amdgcn_mfma_f32_32x32x16_bf16(
                                Af[kh][oi], Bf[kh][wi], acc[oi][wi], 0, 0, 0);
                __builtin_amdgcn_s_setprio(0);
            }

            if (dh == 2 && cb < 15) FEATW((cb + 1) & 1);  // write-late (T14)
            __syncthreads();
        }
    }

    // ---- store: w-coalesced dword stores ----
    const int h = h0 + hrow;
    #pragma unroll
    for (int oi = 0; oi < 2; ++oi)
        #pragma unroll
        for (int wi = 0; wi < 2; ++wi) {
            const int wc = wi * 32 + lo;
            #pragma unroll
            for (int r = 0; r < 16; ++r) {
                const int o = ohalf * 64 + oi * 32 + (r & 3) + ((r >> 2) << 3) + (hi << 2);
                out[((b * OO + o) * HH + h) * WW + wc] = acc[oi][wi][r];
            }
        }
}

extern "C" void kernel_launch(void* const* d_in, const int* in_sizes, int n_in,
                              void* d_out, int out_size, void* d_ws, size_t ws_size,
                              hipStream_t stream) {
    const float* x    = (const float*)d_in[0];
    const float* beta = (const float*)d_in[1];
    const float* spl  = (const float*)d_in[2];
    const float* cf   = (const float*)d_in[3];
    float* out = (float*)d_out;
    uint4* wb  = (uint4*)d_ws;          // 73728 granules = 1.18 MB

    kan_wprep<<<288, 256, 0, stream>>>(beta, spl, cf, wb);
    kan_mfma3<<<BB * 16, 512, 0, stream>>>(x, wb, out);
}